// Round 6
// baseline (184.612 us; speedup 1.0000x reference)
//
#include <hip/hip_runtime.h>
#include <hip/hip_bf16.h>

// Problem constants (match reference)
#define RR 3
#define NN 8192
#define BB 4096
#define IN_DIM 256
#define HID 128
#define OUT 64
#define CAPD 128     // padded list capacity (unique nbr nodes ~ Binom(3224,0.01) ~ 32±5.7)
#define EPS 1e-5f
#define MWN (NN / 64)   // 128 mask words over node space
#define MLPB 16         // slots per MLP block

// ---- prep: multiplicity, membership bitmap, rank compaction, pos->slot ----
__global__ __launch_bounds__(1024) void prep_k(const int* __restrict__ bn,
                                               unsigned long long* __restrict__ memb,
                                               unsigned short* __restrict__ rankg,
                                               unsigned short* __restrict__ nodeof,
                                               float* __restrict__ multf,
                                               int* __restrict__ Ucnt,
                                               unsigned short* __restrict__ pos2slot) {
    __shared__ int smult[NN];                 // 32 KB
    __shared__ unsigned short srank[NN];      // 16 KB
    __shared__ unsigned long long smemb[MWN]; // 1 KB
    __shared__ int sbase[MWN + 1];
    int t = threadIdx.x;
    for (int u = t; u < NN; u += 1024) smult[u] = 0;
    __syncthreads();
    for (int i = t; i < BB; i += 1024) atomicAdd(&smult[bn[i]], 1);
    __syncthreads();
    if (t < MWN) {
        unsigned long long w = 0;
        for (int b = 0; b < 64; ++b) if (smult[t * 64 + b]) w |= (1ull << b);
        smemb[t] = w;
        memb[t] = w;
    }
    __syncthreads();
    if (t == 0) {
        int acc = 0;
        for (int m = 0; m < MWN; ++m) { sbase[m] = acc; acc += (int)__popcll(smemb[m]); }
        sbase[MWN] = acc;
        *Ucnt = acc;
    }
    __syncthreads();
    if (t < MWN) {
        unsigned long long w = smemb[t];
        int p = sbase[t];
        while (w) {
            int b = __builtin_ctzll(w); w &= w - 1;
            int u = t * 64 + b;
            srank[u] = (unsigned short)p;
            rankg[u] = (unsigned short)p;
            nodeof[p] = (unsigned short)u;
            multf[p]  = (float)smult[u];
            ++p;
        }
    }
    __syncthreads();
    for (int i = t; i < BB; i += 1024) pos2slot[i] = srank[bn[i]];
}

// ---- BN1 partial stats: position-major, coalesced float4 rows ----
__global__ __launch_bounds__(256) void bn1p_k(const float* __restrict__ feat,
                                              const int* __restrict__ bn,
                                              float* __restrict__ partial) {
    int b = blockIdx.x;                  // 64 blocks x 64 positions
    int t = threadIdx.x;
    int g = t >> 6, c4 = (t & 63) << 2;  // 4 groups x 64 float4-col-groups
    float4 s = make_float4(0.f, 0.f, 0.f, 0.f), q = s;
    for (int it = 0; it < 16; ++it) {
        int i = b * 64 + g * 16 + it;
        const float4 v = *(const float4*)(feat + (size_t)bn[i] * IN_DIM + c4);
        s.x += v.x; s.y += v.y; s.z += v.z; s.w += v.w;
        q.x += v.x * v.x; q.y += v.y * v.y; q.z += v.z * v.z; q.w += v.w * v.w;
    }
    __shared__ float4 rs_[4][64], rq_[4][64];
    rs_[g][t & 63] = s; rq_[g][t & 63] = q;
    __syncthreads();
    if (t < 64) {
        float4 S = rs_[0][t], Q = rq_[0][t];
        for (int gg = 1; gg < 4; ++gg) {
            float4 a = rs_[gg][t], bq = rq_[gg][t];
            S.x += a.x; S.y += a.y; S.z += a.z; S.w += a.w;
            Q.x += bq.x; Q.y += bq.y; Q.z += bq.z; Q.w += bq.w;
        }
        *(float4*)(partial + ((size_t)(2 * b) * IN_DIM) + t * 4) = S;
        *(float4*)(partial + ((size_t)(2 * b + 1) * IN_DIM) + t * 4) = Q;
    }
}

__global__ __launch_bounds__(256) void bn1f_k(const float* __restrict__ partial,
                                              float* __restrict__ m1,
                                              float* __restrict__ rs1) {
    int c = threadIdx.x;
    float S = 0.f, Q = 0.f;
    for (int b = 0; b < 64; ++b) {
        S += partial[(size_t)(2 * b) * IN_DIM + c];
        Q += partial[(size_t)(2 * b + 1) * IN_DIM + c];
    }
    float m = S / BB;
    m1[c] = m;
    rs1[c] = rsqrtf(Q / BB - m * m + EPS);   // biased variance
}

// ---- xn per unique node slot: xn_c[s] = BN1(feat[nodeof[s]]) ----
__global__ __launch_bounds__(256) void xn_c_k(const float* __restrict__ feat,
                                              const unsigned short* __restrict__ nodeof,
                                              const int* __restrict__ Ucnt,
                                              const float* __restrict__ m1,
                                              const float* __restrict__ rs1,
                                              const float* __restrict__ g1,
                                              const float* __restrict__ b1,
                                              float* __restrict__ xn_c) {
    int s = blockIdx.x;
    if (s >= *Ucnt) return;
    int u = nodeof[s];
    int c = threadIdx.x;
    float v = feat[(size_t)u * IN_DIM + c];
    xn_c[(size_t)s * IN_DIM + c] = (v - m1[c]) * rs1[c] * g1[c] + b1[c];
}

// ---- build per (r, slot): coalesced row read -> bits -> AND membership -> list ----
__global__ __launch_bounds__(256) void build_k(const float* __restrict__ adj,
                                               const unsigned short* __restrict__ nodeof,
                                               const int* __restrict__ Ucnt,
                                               const unsigned long long* __restrict__ memb,
                                               const unsigned short* __restrict__ rankg,
                                               const float* __restrict__ multf,
                                               unsigned short* __restrict__ cols,
                                               int* __restrict__ cnt,
                                               float* __restrict__ dinv) {
    int blk = blockIdx.x;                   // r*4096 + s
    int r = blk >> 12, s = blk & (BB - 1);
    if (s >= *Ucnt) return;
    int u = nodeof[s];
    __shared__ unsigned char nib[2048];
    __shared__ unsigned int rawb[256];
    __shared__ unsigned long long sel[MWN];
    __shared__ int sbase[MWN + 1];
    __shared__ float pdeg[4];
    int t = threadIdx.x;
    // phase A: coalesced read of the 8192-float adjacency row; compress to bits
    const float4* ar4 = (const float4*)(adj + ((size_t)r * NN + u) * NN);
    #pragma unroll
    for (int ch = 0; ch < 8; ++ch) {
        float4 v = ar4[ch * 256 + t];
        nib[ch * 256 + t] = (unsigned char)((v.x != 0.f) | ((v.y != 0.f) << 1) |
                                            ((v.z != 0.f) << 2) | ((v.w != 0.f) << 3));
    }
    __syncthreads();
    {   // assemble u32 word t: cols [32t, 32t+32)
        unsigned long long x = *(const unsigned long long*)&nib[t * 8];
        x = (x | (x >> 4))  & 0x00FF00FF00FF00FFull;
        x = (x | (x >> 8))  & 0x0000FFFF0000FFFFull;
        x = (x | (x >> 16));
        rawb[t] = (unsigned int)x;
    }
    __syncthreads();
    // phase B: select member columns = raw & memb
    if (t < MWN) {
        unsigned long long w = ((unsigned long long)rawb[2 * t + 1] << 32) | rawb[2 * t];
        sel[t] = w & memb[t];
    }
    __syncthreads();
    // phase C: exclusive scan of word popcounts (wave 0, 2 words/lane)
    if (t < 64) {
        int p0 = (int)__popcll(sel[2 * t]);
        int p1 = (int)__popcll(sel[2 * t + 1]);
        int x = p0 + p1, xs = x;
        for (int o = 1; o < 64; o <<= 1) { int y = __shfl_up(xs, o); if (t >= o) xs += y; }
        sbase[2 * t]     = xs - x;
        sbase[2 * t + 1] = xs - p1;
        if (t == 63) sbase[MWN] = xs;
    }
    __syncthreads();
    // phase D: emit slot list + multiplicity-weighted degree
    float wdeg = 0.f;
    if (t < MWN) {
        unsigned long long w = sel[t];
        int p = sbase[t];
        unsigned short* cb = cols + (size_t)blk * CAPD;
        while (w) {
            int b = __builtin_ctzll(w); w &= w - 1;
            int v = t * 64 + b;
            int rv = rankg[v];
            if (p < CAPD) cb[p] = (unsigned short)rv;
            wdeg += multf[rv];
            ++p;
        }
    }
    int lane = t & 63, wv = t >> 6;
    for (int o = 32; o; o >>= 1) wdeg += __shfl_down(wdeg, o);
    if (lane == 0) pdeg[wv] = wdeg;
    __syncthreads();
    if (t == 0) {
        int tot = sbase[MWN];
        cnt[blk] = tot < CAPD ? tot : CAPD;
        dinv[blk] = rsqrtf(pdeg[0] + pdeg[1] + pdeg[2] + pdeg[3] + 1.0f);  // +1 from eye
    }
}

// ---- layer1 aggregation: packed (col,w) pairs, 2 nbrs per b128, float2 cols ----
__global__ __launch_bounds__(128) void agg1_k(const float* __restrict__ xn_c,
                                              const unsigned short* __restrict__ cols,
                                              const int* __restrict__ cnt,
                                              const float* __restrict__ dinv,
                                              const float* __restrict__ multf,
                                              const int* __restrict__ Ucnt,
                                              float* __restrict__ y1) {
    int blk = blockIdx.x;                // r*4096 + s
    int r = blk >> 12, s = blk & (BB - 1);
    if (s >= *Ucnt) return;
    int c = threadIdx.x;                 // 0..127 -> float2 cols [2c,2c+1]
    __shared__ __align__(16) uint2 swp[CAPD];
    int n = cnt[blk];
    if (c < n) {
        int sl = cols[(size_t)blk * CAPD + c];
        swp[c] = make_uint2((unsigned)sl, __float_as_uint(multf[sl] * dinv[(r << 12) + sl]));
    }
    if (c == n && n < CAPD) swp[c] = make_uint2(0u, 0u);   // zero-weight pad
    __syncthreads();
    float di = dinv[blk];
    float2 v = ((const float2*)(xn_c + (size_t)s * IN_DIM))[c];
    float ax = di * v.x, ay = di * v.y;                    // eye diagonal term
    int nn = (n + 1) & ~1;
    const uint4* sw4 = (const uint4*)swp;
    #pragma unroll 2
    for (int kk = 0; kk < (nn >> 1); ++kk) {
        uint4 e = sw4[kk];
        float w0 = __uint_as_float(e.y), w1v = __uint_as_float(e.w);
        float2 x0 = ((const float2*)(xn_c + (size_t)e.x * IN_DIM))[c];
        float2 x1 = ((const float2*)(xn_c + (size_t)e.z * IN_DIM))[c];
        ax += w0 * x0.x + w1v * x1.x;
        ay += w0 * x0.y + w1v * x1.y;
    }
    float2 o = make_float2(ax * di, ay * di);
    *(float2*)(y1 + (size_t)blk * IN_DIM + c * 2) = o;
}

// ---- MLP1: h1 = sigmoid(elu(y1 @ w1)); 16 slots/block; 2 slots x 4 cols/thread ----
__global__ __launch_bounds__(256) void mlp1_k(const float* __restrict__ y1,
                                              const int* __restrict__ Ucnt,
                                              const float* __restrict__ w1,
                                              float* __restrict__ h1) {
    int blk = blockIdx.x;                // r*(BB/MLPB) + chunk
    int r = blk >> 8, base = (blk & 255) * MLPB;
    int U = *Ucnt;
    if (base >= U) return;
    int t = threadIdx.x;
    __shared__ float ys[MLPB][IN_DIM];   // 16 KB
    #pragma unroll
    for (int s = 0; s < MLPB; ++s)
        ys[s][t] = y1[((size_t)(r << 12) + base + s) * IN_DIM + t];
    __syncthreads();
    int p = t >> 5;                      // 0..7 -> slots {2p, 2p+1}
    int c4 = (t & 31) << 2;              // col base
    float4 a0c = make_float4(0.f,0.f,0.f,0.f), a1c = a0c;
    for (int k = 0; k < IN_DIM; k += 4) {
        float4 a0 = *(const float4*)&ys[2 * p][k];
        float4 a1 = *(const float4*)&ys[2 * p + 1][k];
        float4 w0 = *(const float4*)(w1 + (size_t)(k + 0) * HID + c4);
        float4 wv1 = *(const float4*)(w1 + (size_t)(k + 1) * HID + c4);
        float4 wv2 = *(const float4*)(w1 + (size_t)(k + 2) * HID + c4);
        float4 wv3 = *(const float4*)(w1 + (size_t)(k + 3) * HID + c4);
        a0c.x += a0.x*w0.x + a0.y*wv1.x + a0.z*wv2.x + a0.w*wv3.x;
        a0c.y += a0.x*w0.y + a0.y*wv1.y + a0.z*wv2.y + a0.w*wv3.y;
        a0c.z += a0.x*w0.z + a0.y*wv1.z + a0.z*wv2.z + a0.w*wv3.z;
        a0c.w += a0.x*w0.w + a0.y*wv1.w + a0.z*wv2.w + a0.w*wv3.w;
        a1c.x += a1.x*w0.x + a1.y*wv1.x + a1.z*wv2.x + a1.w*wv3.x;
        a1c.y += a1.x*w0.y + a1.y*wv1.y + a1.z*wv2.y + a1.w*wv3.y;
        a1c.z += a1.x*w0.z + a1.y*wv1.z + a1.z*wv2.z + a1.w*wv3.z;
        a1c.w += a1.x*w0.w + a1.y*wv1.w + a1.z*wv2.w + a1.w*wv3.w;
    }
    // elu + sigmoid, store float4 per slot
    float* o0 = h1 + ((size_t)(r << 12) + base + 2 * p) * HID + c4;
    float* o1 = o0 + HID;
    float4 r0, r1;
    #define ACT1(zz) (1.f / (1.f + expf(-((zz) > 0.f ? (zz) : expm1f(zz)))))
    r0.x = ACT1(a0c.x); r0.y = ACT1(a0c.y); r0.z = ACT1(a0c.z); r0.w = ACT1(a0c.w);
    r1.x = ACT1(a1c.x); r1.y = ACT1(a1c.y); r1.z = ACT1(a1c.z); r1.w = ACT1(a1c.w);
    #undef ACT1
    *(float4*)o0 = r0;
    *(float4*)o1 = r1;
}

// ---- layer2 aggregation: 1 wave/slot; packed pairs; float2 cols over HID ----
__global__ __launch_bounds__(64) void agg2_k(const float* __restrict__ h1,
                                             const unsigned short* __restrict__ cols,
                                             const int* __restrict__ cnt,
                                             const float* __restrict__ dinv,
                                             const float* __restrict__ multf,
                                             const int* __restrict__ Ucnt,
                                             float* __restrict__ y2) {
    int blk = blockIdx.x;
    int r = blk >> 12, s = blk & (BB - 1);
    if (s >= *Ucnt) return;
    int c = threadIdx.x;                 // 0..63 -> float2 cols [2c,2c+1]
    __shared__ __align__(16) uint2 swp[CAPD];
    int n = cnt[blk];
    int nn = (n + 1) & ~1;
    for (int idx = c; idx < nn; idx += 64) {
        if (idx < n) {
            int sl = cols[(size_t)blk * CAPD + idx];
            swp[idx] = make_uint2((unsigned)sl, __float_as_uint(multf[sl] * dinv[(r << 12) + sl]));
        } else {
            swp[idx] = make_uint2(0u, 0u);
        }
    }
    __syncthreads();
    const float* h1r = h1 + ((size_t)(r << 12)) * HID;
    float di = dinv[blk];
    float2 v = ((const float2*)(h1r + (size_t)s * HID))[c];
    float ax = di * v.x, ay = di * v.y;
    const uint4* sw4 = (const uint4*)swp;
    #pragma unroll 2
    for (int kk = 0; kk < (nn >> 1); ++kk) {
        uint4 e = sw4[kk];
        float w0 = __uint_as_float(e.y), w1v = __uint_as_float(e.w);
        float2 x0 = ((const float2*)(h1r + (size_t)e.x * HID))[c];
        float2 x1 = ((const float2*)(h1r + (size_t)e.z * HID))[c];
        ax += w0 * x0.x + w1v * x1.x;
        ay += w0 * x0.y + w1v * x1.y;
    }
    float2 o = make_float2(ax * di, ay * di);
    *(float2*)(y2 + (size_t)blk * HID + c * 2) = o;
}

// ---- MLP2: h2 = elu(y2 @ w2); 16 slots/block; 2 slots x 2 cols/thread ----
__global__ __launch_bounds__(256) void mlp2_k(const float* __restrict__ y2,
                                              const int* __restrict__ Ucnt,
                                              const float* __restrict__ w2,
                                              float* __restrict__ h2) {
    int blk = blockIdx.x;
    int r = blk >> 8, base = (blk & 255) * MLPB;
    int U = *Ucnt;
    if (base >= U) return;
    int t = threadIdx.x;
    __shared__ float ys[MLPB][HID];      // 8 KB
    {
        int s2 = t >> 7, cc = t & 127;   // 2 rows per round
        #pragma unroll
        for (int s = s2; s < MLPB; s += 2)
            ys[s][cc] = y2[((size_t)(r << 12) + base + s) * HID + cc];
    }
    __syncthreads();
    int p = t >> 5;                      // slots {2p, 2p+1}
    int c2 = (t & 31) << 1;              // cols [c2, c2+1]
    float2 a0c = make_float2(0.f, 0.f), a1c = a0c;
    for (int k = 0; k < HID; k += 4) {
        float4 a0 = *(const float4*)&ys[2 * p][k];
        float4 a1 = *(const float4*)&ys[2 * p + 1][k];
        float2 w0 = *(const float2*)(w2 + (size_t)(k + 0) * OUT + c2);
        float2 wv1 = *(const float2*)(w2 + (size_t)(k + 1) * OUT + c2);
        float2 wv2 = *(const float2*)(w2 + (size_t)(k + 2) * OUT + c2);
        float2 wv3 = *(const float2*)(w2 + (size_t)(k + 3) * OUT + c2);
        a0c.x += a0.x*w0.x + a0.y*wv1.x + a0.z*wv2.x + a0.w*wv3.x;
        a0c.y += a0.x*w0.y + a0.y*wv1.y + a0.z*wv2.y + a0.w*wv3.y;
        a1c.x += a1.x*w0.x + a1.y*wv1.x + a1.z*wv2.x + a1.w*wv3.x;
        a1c.y += a1.x*w0.y + a1.y*wv1.y + a1.z*wv2.y + a1.w*wv3.y;
    }
    float* o0 = h2 + ((size_t)(r << 12) + base + 2 * p) * OUT + c2;
    float* o1 = o0 + OUT;
    float2 r0, r1;
    r0.x = a0c.x > 0.f ? a0c.x : expm1f(a0c.x);
    r0.y = a0c.y > 0.f ? a0c.y : expm1f(a0c.y);
    r1.x = a1c.x > 0.f ? a1c.x : expm1f(a1c.x);
    r1.y = a1c.y > 0.f ? a1c.y : expm1f(a1c.y);
    *(float2*)o0 = r0;
    *(float2*)o1 = r1;
}

// ---- BN2 stats per (relation, column): multiplicity-weighted over slots ----
__global__ __launch_bounds__(256) void bn2_stats_k(const float* __restrict__ h2,
                                                   const float* __restrict__ multf,
                                                   const int* __restrict__ Ucnt,
                                                   float* __restrict__ m2,
                                                   float* __restrict__ rs2) {
    int ro = blockIdx.x;             // r*OUT + o
    int r = ro >> 6, o = ro & (OUT - 1);
    int U = *Ucnt;
    float s = 0.f, q = 0.f;
    for (int sl = threadIdx.x; sl < U; sl += 256) {
        float m = multf[sl];
        float v = h2[(size_t)((r << 12) + sl) * OUT + o];
        s += m * v; q += m * v * v;
    }
    int lane = threadIdx.x & 63, wv = threadIdx.x >> 6;
    for (int off = 32; off; off >>= 1) { s += __shfl_down(s, off); q += __shfl_down(q, off); }
    __shared__ float ps[4], pq[4];
    if (lane == 0) { ps[wv] = s; pq[wv] = q; }
    __syncthreads();
    if (threadIdx.x == 0) {
        float S = ps[0] + ps[1] + ps[2] + ps[3];
        float Q = pq[0] + pq[1] + pq[2] + pq[3];
        float m = S / BB;                 // sum of mult == BB positions
        float v = Q / BB - m * m;
        m2[ro] = m;
        rs2[ro] = rsqrtf(v + EPS);
    }
}

// ---- finalize: out[i] = relu(mean_r BN2(h2[r, slot(i)])) ----
__global__ __launch_bounds__(256) void finalize_k(const float* __restrict__ h2,
                                                  const unsigned short* __restrict__ pos2slot,
                                                  const float* __restrict__ m2,
                                                  const float* __restrict__ rs2,
                                                  const float* __restrict__ g2,
                                                  const float* __restrict__ b2,
                                                  float* __restrict__ out) {
    int idx = blockIdx.x * 256 + threadIdx.x;  // i*OUT + o
    if (idx >= BB * OUT) return;
    int i = idx >> 6, o = idx & (OUT - 1);
    int sl = pos2slot[i];
    float s = 0.f;
    for (int r = 0; r < RR; ++r) {
        float v = h2[(size_t)((r << 12) + sl) * OUT + o];
        s += (v - m2[r * OUT + o]) * rs2[r * OUT + o] * g2[o] + b2[o];
    }
    s *= (1.0f / RR);
    out[idx] = s > 0.f ? s : 0.f;
}

extern "C" void kernel_launch(void* const* d_in, const int* in_sizes, int n_in,
                              void* d_out, int out_size, void* d_ws, size_t ws_size,
                              hipStream_t stream) {
    const float* feat = (const float*)d_in[0];
    const float* adj  = (const float*)d_in[1];
    const int*   bn   = (const int*)d_in[2];
    const float* w1   = (const float*)d_in[3];
    const float* w2   = (const float*)d_in[4];
    const float* g1   = (const float*)d_in[5];
    const float* b1   = (const float*)d_in[6];
    const float* g2   = (const float*)d_in[7];
    const float* b2   = (const float*)d_in[8];
    float* out = (float*)d_out;

    // workspace layout (256-aligned offsets)
    char* ws = (char*)d_ws;
    size_t off = 0;
    auto alloc = [&](size_t bytes) { size_t o = off; off += (bytes + 255) & ~(size_t)255; return o; };
    unsigned long long* memb = (unsigned long long*)(ws + alloc(MWN * 8));      // 1 KB
    unsigned short* rankg    = (unsigned short*)(ws + alloc(NN * 2));           // 16 KB
    unsigned short* nodeof   = (unsigned short*)(ws + alloc(BB * 2));           // 8 KB
    float* multf             = (float*)(ws + alloc(BB * 4));                    // 16 KB
    int* Ucnt                = (int*)(ws + alloc(4));
    unsigned short* pos2slot = (unsigned short*)(ws + alloc(BB * 2));           // 8 KB
    float* partial           = (float*)(ws + alloc(128 * IN_DIM * 4));          // 128 KB
    float* m1                = (float*)(ws + alloc(IN_DIM * 4));
    float* rs1               = (float*)(ws + alloc(IN_DIM * 4));
    float* m2                = (float*)(ws + alloc(RR * OUT * 4));
    float* rs2               = (float*)(ws + alloc(RR * OUT * 4));
    float* xn_c              = (float*)(ws + alloc((size_t)BB * IN_DIM * 4));   // 4 MB
    unsigned short* cols     = (unsigned short*)(ws + alloc((size_t)RR * BB * CAPD * 2)); // 3.1 MB
    int* cnt                 = (int*)(ws + alloc((size_t)RR * BB * 4));         // 48 KB
    float* dinv              = (float*)(ws + alloc((size_t)RR * BB * 4));       // 48 KB
    float* y1                = (float*)(ws + alloc((size_t)RR * BB * IN_DIM * 4)); // 12.6 MB
    float* h1                = (float*)(ws + alloc((size_t)RR * BB * HID * 4)); // 6.3 MB
    float* y2                = (float*)(ws + alloc((size_t)RR * BB * HID * 4)); // 6.3 MB
    float* h2                = (float*)(ws + alloc((size_t)RR * BB * OUT * 4)); // 3.1 MB

    prep_k<<<1, 1024, 0, stream>>>(bn, memb, rankg, nodeof, multf, Ucnt, pos2slot);
    bn1p_k<<<64, 256, 0, stream>>>(feat, bn, partial);
    bn1f_k<<<1, 256, 0, stream>>>(partial, m1, rs1);
    xn_c_k<<<BB, 256, 0, stream>>>(feat, nodeof, Ucnt, m1, rs1, g1, b1, xn_c);
    build_k<<<RR * BB, 256, 0, stream>>>(adj, nodeof, Ucnt, memb, rankg, multf, cols, cnt, dinv);
    agg1_k<<<RR * BB, 128, 0, stream>>>(xn_c, cols, cnt, dinv, multf, Ucnt, y1);
    mlp1_k<<<RR * 256, 256, 0, stream>>>(y1, Ucnt, w1, h1);
    agg2_k<<<RR * BB, 64, 0, stream>>>(h1, cols, cnt, dinv, multf, Ucnt, y2);
    mlp2_k<<<RR * 256, 256, 0, stream>>>(y2, Ucnt, w2, h2);
    bn2_stats_k<<<RR * OUT, 256, 0, stream>>>(h2, multf, Ucnt, m2, rs2);
    finalize_k<<<(BB * OUT + 255) / 256, 256, 0, stream>>>(h2, pos2slot, m2, rs2, g2, b2, out);
}

// Round 7
// 164.918 us; speedup vs baseline: 1.1194x; 1.1194x over previous
//
#include <hip/hip_runtime.h>
#include <hip/hip_bf16.h>

// Problem constants (match reference)
#define RR 3
#define NN 8192
#define BB 4096
#define IN_DIM 256
#define HID 128
#define OUT 64
#define CAPD 128     // padded list capacity (unique nbr nodes ~ Binom(3224,0.01) ~ 32±5.7)
#define EPS 1e-5f
#define MWN (NN / 64)   // 128 mask words over node space
#define MLPB 16         // slots per MLP block

// ---- K1: blocks 0..255 = BN1 per-column stats -> affine consts; block 256 = prep ----
__global__ __launch_bounds__(256) void k1_bn1_prep_k(const float* __restrict__ feat,
                                                     const int* __restrict__ bn,
                                                     const float* __restrict__ g1,
                                                     const float* __restrict__ b1,
                                                     float* __restrict__ af,
                                                     float* __restrict__ bfv,
                                                     unsigned long long* __restrict__ memb,
                                                     unsigned short* __restrict__ rankg,
                                                     unsigned short* __restrict__ nodeof,
                                                     float* __restrict__ multf,
                                                     int* __restrict__ Ucnt,
                                                     unsigned short* __restrict__ pos2slot) {
    __shared__ int smult[NN];                 // 32 KB (prep block only)
    __shared__ unsigned short srank[NN];      // 16 KB
    __shared__ unsigned long long smemb[MWN]; // 1 KB
    __shared__ int sbase[MWN + 1];
    __shared__ float ps[4], pq[4];
    int t = threadIdx.x;
    if (blockIdx.x < IN_DIM) {
        // BN1 stats for column c
        int c = blockIdx.x;
        float s = 0.f, q = 0.f;
        for (int i = t; i < BB; i += 256) {
            float v = feat[(size_t)bn[i] * IN_DIM + c];
            s += v; q += v * v;
        }
        int lane = t & 63, wv = t >> 6;
        for (int o = 32; o; o >>= 1) { s += __shfl_down(s, o); q += __shfl_down(q, o); }
        if (lane == 0) { ps[wv] = s; pq[wv] = q; }
        __syncthreads();
        if (t == 0) {
            float S = ps[0] + ps[1] + ps[2] + ps[3];
            float Q = pq[0] + pq[1] + pq[2] + pq[3];
            float m = S / BB;
            float rs = rsqrtf(Q / BB - m * m + EPS);   // biased variance
            float a = rs * g1[c];
            af[c]  = a;
            bfv[c] = b1[c] - m * a;
        }
        return;
    }
    // ---- prep (single block, 256 threads) ----
    for (int u = t; u < NN; u += 256) smult[u] = 0;
    __syncthreads();
    for (int i = t; i < BB; i += 256) atomicAdd(&smult[bn[i]], 1);
    __syncthreads();
    if (t < MWN) {
        unsigned long long w = 0;
        for (int b = 0; b < 64; ++b) if (smult[t * 64 + b]) w |= (1ull << b);
        smemb[t] = w;
        memb[t] = w;
    }
    __syncthreads();
    if (t == 0) {
        int acc = 0;
        for (int m = 0; m < MWN; ++m) { sbase[m] = acc; acc += (int)__popcll(smemb[m]); }
        sbase[MWN] = acc;
        *Ucnt = acc;
    }
    __syncthreads();
    if (t < MWN) {
        unsigned long long w = smemb[t];
        int p = sbase[t];
        while (w) {
            int b = __builtin_ctzll(w); w &= w - 1;
            int u = t * 64 + b;
            srank[u] = (unsigned short)p;
            rankg[u] = (unsigned short)p;
            nodeof[p] = (unsigned short)u;
            multf[p]  = (float)smult[u];
            ++p;
        }
    }
    __syncthreads();
    for (int i = t; i < BB; i += 256) pos2slot[i] = srank[bn[i]];
}

// ---- build per (r, slot): coalesced row read -> bits -> AND membership -> packed list ----
__global__ __launch_bounds__(256) void build_k(const float* __restrict__ adj,
                                               const unsigned short* __restrict__ nodeof,
                                               const int* __restrict__ Ucnt,
                                               const unsigned long long* __restrict__ memb,
                                               const unsigned short* __restrict__ rankg,
                                               const float* __restrict__ multf,
                                               unsigned* __restrict__ cols,
                                               int* __restrict__ cnt,
                                               float* __restrict__ dinv) {
    int blk = blockIdx.x;                   // r*4096 + s
    int r = blk >> 12, s = blk & (BB - 1);
    if (s >= *Ucnt) return;
    int u = nodeof[s];
    __shared__ unsigned char nib[2048];
    __shared__ unsigned int rawb[256];
    __shared__ unsigned long long sel[MWN];
    __shared__ int sbase[MWN + 1];
    __shared__ float pdeg[4];
    int t = threadIdx.x;
    // phase A: coalesced read of the 8192-float adjacency row; compress to bits
    const float4* ar4 = (const float4*)(adj + ((size_t)r * NN + u) * NN);
    #pragma unroll
    for (int ch = 0; ch < 8; ++ch) {
        float4 v = ar4[ch * 256 + t];
        nib[ch * 256 + t] = (unsigned char)((v.x != 0.f) | ((v.y != 0.f) << 1) |
                                            ((v.z != 0.f) << 2) | ((v.w != 0.f) << 3));
    }
    __syncthreads();
    {   // assemble u32 word t: cols [32t, 32t+32)
        unsigned long long x = *(const unsigned long long*)&nib[t * 8];
        x = (x | (x >> 4))  & 0x00FF00FF00FF00FFull;
        x = (x | (x >> 8))  & 0x0000FFFF0000FFFFull;
        x = (x | (x >> 16));
        rawb[t] = (unsigned int)x;
    }
    __syncthreads();
    // phase B: select member columns = raw & memb
    if (t < MWN) {
        unsigned long long w = ((unsigned long long)rawb[2 * t + 1] << 32) | rawb[2 * t];
        sel[t] = w & memb[t];
    }
    __syncthreads();
    // phase C: exclusive scan of word popcounts (wave 0, 2 words/lane)
    if (t < 64) {
        int p0 = (int)__popcll(sel[2 * t]);
        int p1 = (int)__popcll(sel[2 * t + 1]);
        int x = p0 + p1, xs = x;
        for (int o = 1; o < 64; o <<= 1) { int y = __shfl_up(xs, o); if (t >= o) xs += y; }
        sbase[2 * t]     = xs - x;
        sbase[2 * t + 1] = xs - p1;
        if (t == 63) sbase[MWN] = xs;
    }
    __syncthreads();
    // phase D: emit packed (slot<<13)|node list + multiplicity-weighted degree
    float wdeg = 0.f;
    if (t < MWN) {
        unsigned long long w = sel[t];
        int p = sbase[t];
        unsigned* cb = cols + (size_t)blk * CAPD;
        while (w) {
            int b = __builtin_ctzll(w); w &= w - 1;
            int v = t * 64 + b;              // node id (13 bits)
            int rv = rankg[v];               // slot id (12 bits)
            if (p < CAPD) cb[p] = ((unsigned)rv << 13) | (unsigned)v;
            wdeg += multf[rv];
            ++p;
        }
    }
    int lane = t & 63, wv = t >> 6;
    for (int o = 32; o; o >>= 1) wdeg += __shfl_down(wdeg, o);
    if (lane == 0) pdeg[wv] = wdeg;
    __syncthreads();
    if (t == 0) {
        int tot = sbase[MWN];
        cnt[blk] = tot < CAPD ? tot : CAPD;
        dinv[blk] = rsqrtf(pdeg[0] + pdeg[1] + pdeg[2] + pdeg[3] + 1.0f);  // +1 from eye
    }
}

// ---- agg1: y1 = A_hat @ BN1(x) via raw-feat agg + affine epilogue ----
__global__ __launch_bounds__(256) void agg1_k(const float* __restrict__ feat,
                                              const unsigned* __restrict__ cols,
                                              const int* __restrict__ cnt,
                                              const float* __restrict__ dinv,
                                              const float* __restrict__ multf,
                                              const unsigned short* __restrict__ nodeof,
                                              const int* __restrict__ Ucnt,
                                              const float* __restrict__ af,
                                              const float* __restrict__ bfv,
                                              float* __restrict__ y1) {
    int blk = blockIdx.x;                // r*4096 + s
    int r = blk >> 12, s = blk & (BB - 1);
    if (s >= *Ucnt) return;
    int c = threadIdx.x;                 // one column 0..255
    __shared__ unsigned short snode[CAPD];
    __shared__ float swl[CAPD];
    int n = cnt[blk];
    if (c < n) {
        unsigned e = cols[(size_t)blk * CAPD + c];
        int sl = e >> 13;
        snode[c] = (unsigned short)(e & 8191u);
        swl[c] = multf[sl] * dinv[(r << 12) + sl];
    }
    __syncthreads();
    float di = dinv[blk];
    float acc = di * feat[(size_t)nodeof[s] * IN_DIM + c];   // eye diagonal term (raw x)
    float sw = 0.f;
    #pragma unroll 4
    for (int k = 0; k < n; ++k) {
        float w = swl[k];
        sw += w;
        acc += w * feat[(size_t)snode[k] * IN_DIM + c];
    }
    float raw = acc * di;                // di^2 x_s + di * sum(w x)
    float f = di * (di + sw);            // rowsum of A_hat for this row
    y1[(size_t)blk * IN_DIM + c] = af[c] * raw + bfv[c] * f;
}

// ---- MLP1: h1 = sigmoid(elu(y1 @ w1)); 16 slots/block, w1 amortized ----
__global__ __launch_bounds__(256) void mlp1_k(const float* __restrict__ y1,
                                              const int* __restrict__ Ucnt,
                                              const float* __restrict__ w1,
                                              float* __restrict__ h1) {
    int blk = blockIdx.x;                // r*(BB/MLPB) + chunk
    int r = blk / (BB / MLPB), base = (blk % (BB / MLPB)) * MLPB;
    int U = *Ucnt;
    if (base >= U) return;
    int t = threadIdx.x;
    __shared__ float ys[MLPB][IN_DIM];   // 16 KB
    #pragma unroll
    for (int s = 0; s < MLPB; ++s) {
        int slot = base + s;
        ys[s][t] = (slot < U) ? y1[((size_t)(r << 12) + slot) * IN_DIM + t] : 0.f;
    }
    __syncthreads();
    int c = t & 127, g = t >> 7;         // g in {0,1}: slots g*8 .. g*8+7
    float acc[8] = {0.f};
    for (int k = 0; k < IN_DIM; ++k) {
        float wv = w1[k * HID + c];
        #pragma unroll
        for (int j = 0; j < 8; ++j) acc[j] += ys[g * 8 + j][k] * wv;
    }
    #pragma unroll
    for (int j = 0; j < 8; ++j) {
        int slot = base + g * 8 + j;
        if (slot < U) {
            float z = acc[j];
            float e = z > 0.f ? z : expm1f(z);            // elu
            h1[((size_t)(r << 12) + slot) * HID + c] = 1.f / (1.f + expf(-e));  // sigmoid
        }
    }
}

// ---- agg2: y2 = A_hat @ h1 (slot-indexed h1; unpack slot from packed cols) ----
__global__ __launch_bounds__(128) void agg2_k(const float* __restrict__ h1,
                                              const unsigned* __restrict__ cols,
                                              const int* __restrict__ cnt,
                                              const float* __restrict__ dinv,
                                              const float* __restrict__ multf,
                                              const int* __restrict__ Ucnt,
                                              float* __restrict__ y2) {
    int blk = blockIdx.x;
    int r = blk >> 12, s = blk & (BB - 1);
    if (s >= *Ucnt) return;
    int c = threadIdx.x;                 // 0..127
    __shared__ unsigned short scl[CAPD];
    __shared__ float swl[CAPD];
    int n = cnt[blk];
    if (c < n) {
        unsigned e = cols[(size_t)blk * CAPD + c];
        int sl = e >> 13;
        scl[c] = (unsigned short)sl;
        swl[c] = multf[sl] * dinv[(r << 12) + sl];
    }
    __syncthreads();
    const float* h1r = h1 + ((size_t)(r << 12)) * HID;
    float di = dinv[blk];
    float acc = di * h1r[(size_t)s * HID + c];
    #pragma unroll 4
    for (int k = 0; k < n; ++k) {
        acc += swl[k] * h1r[(size_t)scl[k] * HID + c];
    }
    y2[(size_t)blk * HID + c] = acc * di;
}

// ---- MLP2: h2 = elu(y2 @ w2); 16 slots/block, w2 amortized ----
__global__ __launch_bounds__(256) void mlp2_k(const float* __restrict__ y2,
                                              const int* __restrict__ Ucnt,
                                              const float* __restrict__ w2,
                                              float* __restrict__ h2) {
    int blk = blockIdx.x;
    int r = blk / (BB / MLPB), base = (blk % (BB / MLPB)) * MLPB;
    int U = *Ucnt;
    if (base >= U) return;
    int t = threadIdx.x;
    __shared__ float ys[MLPB][HID];      // 8 KB
    #pragma unroll
    for (int s = t >> 7; s < MLPB; s += 2) {
        int slot = base + s;
        ys[s][t & 127] = (slot < U) ? y2[((size_t)(r << 12) + slot) * HID + (t & 127)] : 0.f;
    }
    __syncthreads();
    int c = t & 63, g = t >> 6;          // g in 0..3: slots g*4 .. g*4+3
    float acc[4] = {0.f};
    for (int k = 0; k < HID; ++k) {
        float wv = w2[k * OUT + c];
        #pragma unroll
        for (int j = 0; j < 4; ++j) acc[j] += ys[g * 4 + j][k] * wv;
    }
    #pragma unroll
    for (int j = 0; j < 4; ++j) {
        int slot = base + g * 4 + j;
        if (slot < U) {
            float z = acc[j];
            h2[((size_t)(r << 12) + slot) * OUT + c] = z > 0.f ? z : expm1f(z);  // elu
        }
    }
}

// ---- BN2 stats per (relation, column): multiplicity-weighted over slots ----
__global__ __launch_bounds__(256) void bn2_stats_k(const float* __restrict__ h2,
                                                   const float* __restrict__ multf,
                                                   const int* __restrict__ Ucnt,
                                                   float* __restrict__ m2,
                                                   float* __restrict__ rs2) {
    int ro = blockIdx.x;             // r*OUT + o
    int r = ro >> 6, o = ro & (OUT - 1);
    int U = *Ucnt;
    float s = 0.f, q = 0.f;
    for (int sl = threadIdx.x; sl < U; sl += 256) {
        float m = multf[sl];
        float v = h2[(size_t)((r << 12) + sl) * OUT + o];
        s += m * v; q += m * v * v;
    }
    int lane = threadIdx.x & 63, wv = threadIdx.x >> 6;
    for (int off = 32; off; off >>= 1) { s += __shfl_down(s, off); q += __shfl_down(q, off); }
    __shared__ float ps[4], pq[4];
    if (lane == 0) { ps[wv] = s; pq[wv] = q; }
    __syncthreads();
    if (threadIdx.x == 0) {
        float S = ps[0] + ps[1] + ps[2] + ps[3];
        float Q = pq[0] + pq[1] + pq[2] + pq[3];
        float m = S / BB;                 // sum of mult == BB positions
        float v = Q / BB - m * m;
        m2[ro] = m;
        rs2[ro] = rsqrtf(v + EPS);
    }
}

// ---- finalize: out[i] = relu(mean_r BN2(h2[r, slot(i)])) ----
__global__ __launch_bounds__(256) void finalize_k(const float* __restrict__ h2,
                                                  const unsigned short* __restrict__ pos2slot,
                                                  const float* __restrict__ m2,
                                                  const float* __restrict__ rs2,
                                                  const float* __restrict__ g2,
                                                  const float* __restrict__ b2,
                                                  float* __restrict__ out) {
    int idx = blockIdx.x * 256 + threadIdx.x;  // i*OUT + o
    if (idx >= BB * OUT) return;
    int i = idx >> 6, o = idx & (OUT - 1);
    int sl = pos2slot[i];
    float s = 0.f;
    for (int r = 0; r < RR; ++r) {
        float v = h2[(size_t)((r << 12) + sl) * OUT + o];
        s += (v - m2[r * OUT + o]) * rs2[r * OUT + o] * g2[o] + b2[o];
    }
    s *= (1.0f / RR);
    out[idx] = s > 0.f ? s : 0.f;
}

extern "C" void kernel_launch(void* const* d_in, const int* in_sizes, int n_in,
                              void* d_out, int out_size, void* d_ws, size_t ws_size,
                              hipStream_t stream) {
    const float* feat = (const float*)d_in[0];
    const float* adj  = (const float*)d_in[1];
    const int*   bn   = (const int*)d_in[2];
    const float* w1   = (const float*)d_in[3];
    const float* w2   = (const float*)d_in[4];
    const float* g1   = (const float*)d_in[5];
    const float* b1   = (const float*)d_in[6];
    const float* g2   = (const float*)d_in[7];
    const float* b2   = (const float*)d_in[8];
    float* out = (float*)d_out;

    // workspace layout (256-aligned offsets)
    char* ws = (char*)d_ws;
    size_t off = 0;
    auto alloc = [&](size_t bytes) { size_t o = off; off += (bytes + 255) & ~(size_t)255; return o; };
    unsigned long long* memb = (unsigned long long*)(ws + alloc(MWN * 8));      // 1 KB
    unsigned short* rankg    = (unsigned short*)(ws + alloc(NN * 2));           // 16 KB
    unsigned short* nodeof   = (unsigned short*)(ws + alloc(BB * 2));           // 8 KB
    float* multf             = (float*)(ws + alloc(BB * 4));                    // 16 KB
    int* Ucnt                = (int*)(ws + alloc(4));
    unsigned short* pos2slot = (unsigned short*)(ws + alloc(BB * 2));           // 8 KB
    float* af                = (float*)(ws + alloc(IN_DIM * 4));
    float* bfv               = (float*)(ws + alloc(IN_DIM * 4));
    float* m2                = (float*)(ws + alloc(RR * OUT * 4));
    float* rs2               = (float*)(ws + alloc(RR * OUT * 4));
    unsigned* cols           = (unsigned*)(ws + alloc((size_t)RR * BB * CAPD * 4)); // 6.3 MB
    int* cnt                 = (int*)(ws + alloc((size_t)RR * BB * 4));         // 48 KB
    float* dinv              = (float*)(ws + alloc((size_t)RR * BB * 4));       // 48 KB
    float* y1                = (float*)(ws + alloc((size_t)RR * BB * IN_DIM * 4)); // 12.6 MB
    float* h1                = (float*)(ws + alloc((size_t)RR * BB * HID * 4)); // 6.3 MB
    float* y2                = (float*)(ws + alloc((size_t)RR * BB * HID * 4)); // 6.3 MB
    float* h2                = (float*)(ws + alloc((size_t)RR * BB * OUT * 4)); // 3.1 MB

    k1_bn1_prep_k<<<IN_DIM + 1, 256, 0, stream>>>(feat, bn, g1, b1, af, bfv,
                                                  memb, rankg, nodeof, multf, Ucnt, pos2slot);
    build_k<<<RR * BB, 256, 0, stream>>>(adj, nodeof, Ucnt, memb, rankg, multf, cols, cnt, dinv);
    agg1_k<<<RR * BB, 256, 0, stream>>>(feat, cols, cnt, dinv, multf, nodeof, Ucnt, af, bfv, y1);
    mlp1_k<<<RR * (BB / MLPB), 256, 0, stream>>>(y1, Ucnt, w1, h1);
    agg2_k<<<RR * BB, 128, 0, stream>>>(h1, cols, cnt, dinv, multf, Ucnt, y2);
    mlp2_k<<<RR * (BB / MLPB), 256, 0, stream>>>(y2, Ucnt, w2, h2);
    bn2_stats_k<<<RR * OUT, 256, 0, stream>>>(h2, multf, Ucnt, m2, rs2);
    finalize_k<<<(BB * OUT + 255) / 256, 256, 0, stream>>>(h2, pos2slot, m2, rs2, g2, b2, out);
}

// Round 8
// 154.084 us; speedup vs baseline: 1.1981x; 1.0703x over previous
//
#include <hip/hip_runtime.h>
#include <hip/hip_bf16.h>

// Problem constants (match reference)
#define RR 3
#define NN 8192
#define BB 4096
#define IN_DIM 256
#define HID 128
#define OUT 64
#define CAPD 128     // padded list capacity (unique nbr nodes ~ Binom(3224,0.01) ~ 32±5.7)
#define EPS 1e-5f
#define MWN (NN / 64)   // 128 mask words over node space

// ---- K1: blocks 0..255 = BN1 per-column stats -> affine consts; block 256 = prep ----
__global__ __launch_bounds__(256) void k1_bn1_prep_k(const float* __restrict__ feat,
                                                     const int* __restrict__ bn,
                                                     const float* __restrict__ g1,
                                                     const float* __restrict__ b1,
                                                     float* __restrict__ af,
                                                     float* __restrict__ bfv,
                                                     unsigned long long* __restrict__ memb,
                                                     unsigned short* __restrict__ rankg,
                                                     unsigned short* __restrict__ nodeof,
                                                     float* __restrict__ multf,
                                                     int* __restrict__ Ucnt,
                                                     unsigned short* __restrict__ pos2slot) {
    __shared__ int smult[NN];                 // 32 KB (prep block only)
    __shared__ unsigned short srank[NN];      // 16 KB
    __shared__ unsigned long long smemb[MWN]; // 1 KB
    __shared__ int sbase[MWN + 1];
    __shared__ float ps[4], pq[4];
    int t = threadIdx.x;
    if (blockIdx.x < IN_DIM) {
        // BN1 stats for column c
        int c = blockIdx.x;
        float s = 0.f, q = 0.f;
        for (int i = t; i < BB; i += 256) {
            float v = feat[(size_t)bn[i] * IN_DIM + c];
            s += v; q += v * v;
        }
        int lane = t & 63, wv = t >> 6;
        for (int o = 32; o; o >>= 1) { s += __shfl_down(s, o); q += __shfl_down(q, o); }
        if (lane == 0) { ps[wv] = s; pq[wv] = q; }
        __syncthreads();
        if (t == 0) {
            float S = ps[0] + ps[1] + ps[2] + ps[3];
            float Q = pq[0] + pq[1] + pq[2] + pq[3];
            float m = S / BB;
            float rs = rsqrtf(Q / BB - m * m + EPS);   // biased variance
            float a = rs * g1[c];
            af[c]  = a;
            bfv[c] = b1[c] - m * a;
        }
        return;
    }
    // ---- prep (single block, 256 threads) ----
    for (int u = t; u < NN; u += 256) smult[u] = 0;
    __syncthreads();
    for (int i = t; i < BB; i += 256) atomicAdd(&smult[bn[i]], 1);
    __syncthreads();
    if (t < MWN) {
        unsigned long long w = 0;
        for (int b = 0; b < 64; ++b) if (smult[t * 64 + b]) w |= (1ull << b);
        smemb[t] = w;
        memb[t] = w;
    }
    __syncthreads();
    if (t == 0) {
        int acc = 0;
        for (int m = 0; m < MWN; ++m) { sbase[m] = acc; acc += (int)__popcll(smemb[m]); }
        sbase[MWN] = acc;
        *Ucnt = acc;
    }
    __syncthreads();
    if (t < MWN) {
        unsigned long long w = smemb[t];
        int p = sbase[t];
        while (w) {
            int b = __builtin_ctzll(w); w &= w - 1;
            int u = t * 64 + b;
            srank[u] = (unsigned short)p;
            rankg[u] = (unsigned short)p;
            nodeof[p] = (unsigned short)u;
            multf[p]  = (float)smult[u];
            ++p;
        }
    }
    __syncthreads();
    for (int i = t; i < BB; i += 256) pos2slot[i] = srank[bn[i]];
}

// ---- build per (r, slot): coalesced row read -> bits -> AND membership -> packed list ----
__global__ __launch_bounds__(256) void build_k(const float* __restrict__ adj,
                                               const unsigned short* __restrict__ nodeof,
                                               const int* __restrict__ Ucnt,
                                               const unsigned long long* __restrict__ memb,
                                               const unsigned short* __restrict__ rankg,
                                               const float* __restrict__ multf,
                                               unsigned* __restrict__ cols,
                                               int* __restrict__ cnt,
                                               float* __restrict__ dinv) {
    int blk = blockIdx.x;                   // r*4096 + s
    int r = blk >> 12, s = blk & (BB - 1);
    if (s >= *Ucnt) return;
    int u = nodeof[s];
    __shared__ unsigned char nib[2048];
    __shared__ unsigned int rawb[256];
    __shared__ unsigned long long sel[MWN];
    __shared__ int sbase[MWN + 1];
    __shared__ float pdeg[4];
    int t = threadIdx.x;
    // phase A: coalesced read of the 8192-float adjacency row; compress to bits
    const float4* ar4 = (const float4*)(adj + ((size_t)r * NN + u) * NN);
    #pragma unroll
    for (int ch = 0; ch < 8; ++ch) {
        float4 v = ar4[ch * 256 + t];
        nib[ch * 256 + t] = (unsigned char)((v.x != 0.f) | ((v.y != 0.f) << 1) |
                                            ((v.z != 0.f) << 2) | ((v.w != 0.f) << 3));
    }
    __syncthreads();
    {   // assemble u32 word t: cols [32t, 32t+32)
        unsigned long long x = *(const unsigned long long*)&nib[t * 8];
        x = (x | (x >> 4))  & 0x00FF00FF00FF00FFull;
        x = (x | (x >> 8))  & 0x0000FFFF0000FFFFull;
        x = (x | (x >> 16));
        rawb[t] = (unsigned int)x;
    }
    __syncthreads();
    // phase B: select member columns = raw & memb
    if (t < MWN) {
        unsigned long long w = ((unsigned long long)rawb[2 * t + 1] << 32) | rawb[2 * t];
        sel[t] = w & memb[t];
    }
    __syncthreads();
    // phase C: exclusive scan of word popcounts (wave 0, 2 words/lane)
    if (t < 64) {
        int p0 = (int)__popcll(sel[2 * t]);
        int p1 = (int)__popcll(sel[2 * t + 1]);
        int x = p0 + p1, xs = x;
        for (int o = 1; o < 64; o <<= 1) { int y = __shfl_up(xs, o); if (t >= o) xs += y; }
        sbase[2 * t]     = xs - x;
        sbase[2 * t + 1] = xs - p1;
        if (t == 63) sbase[MWN] = xs;
    }
    __syncthreads();
    // phase D: emit packed (slot<<13)|node list + multiplicity-weighted degree
    float wdeg = 0.f;
    if (t < MWN) {
        unsigned long long w = sel[t];
        int p = sbase[t];
        unsigned* cb = cols + (size_t)blk * CAPD;
        while (w) {
            int b = __builtin_ctzll(w); w &= w - 1;
            int v = t * 64 + b;              // node id (13 bits)
            int rv = rankg[v];               // slot id (12 bits)
            if (p < CAPD) cb[p] = ((unsigned)rv << 13) | (unsigned)v;
            wdeg += multf[rv];
            ++p;
        }
    }
    int lane = t & 63, wv = t >> 6;
    for (int o = 32; o; o >>= 1) wdeg += __shfl_down(wdeg, o);
    if (lane == 0) pdeg[wv] = wdeg;
    __syncthreads();
    if (t == 0) {
        int tot = sbase[MWN];
        cnt[blk] = tot < CAPD ? tot : CAPD;
        dinv[blk] = rsqrtf(pdeg[0] + pdeg[1] + pdeg[2] + pdeg[3] + 1.0f);  // +1 from eye
    }
}

// ---- fused agg1+mlp1: 16 slots/block; agg raw feat + affine -> LDS -> GEMM+act ----
__global__ __launch_bounds__(256) void aggmlp1_k(const float* __restrict__ feat,
                                                 const unsigned* __restrict__ cols,
                                                 const int* __restrict__ cnt,
                                                 const float* __restrict__ dinv,
                                                 const float* __restrict__ multf,
                                                 const unsigned short* __restrict__ nodeof,
                                                 const int* __restrict__ Ucnt,
                                                 const float* __restrict__ af,
                                                 const float* __restrict__ bfv,
                                                 const float* __restrict__ w1,
                                                 float* __restrict__ h1) {
    int blk = blockIdx.x;                 // r*256 + chunk
    int r = blk >> 8, base = (blk & 255) << 4;
    int U = *Ucnt;
    if (base >= U) return;
    int t = threadIdx.x, lane = t & 63, wv = t >> 6;
    __shared__ unsigned short snode[16][CAPD];   // 4 KB
    __shared__ float swl[16][CAPD];              // 8 KB
    __shared__ float ys[16][IN_DIM];             // 16 KB
    __shared__ float sdii[16], ssw[16];
    __shared__ int sn[16];
    // stage 16 lists (wave wv handles s16 = wv, wv+4, wv+8, wv+12)
    for (int s16 = wv; s16 < 16; s16 += 4) {
        int slot = base + s16;
        int n = (slot < U) ? cnt[(r << 12) + slot] : 0;
        if (lane == 0) { sn[s16] = n; sdii[s16] = (slot < U) ? dinv[(r << 12) + slot] : 0.f; }
        size_t cb = ((size_t)(r << 12) + slot) * CAPD;
        float swsum = 0.f;
        for (int idx = lane; idx < n; idx += 64) {
            unsigned e = cols[cb + idx];
            int sl = e >> 13;
            snode[s16][idx] = (unsigned short)(e & 8191u);
            float w = multf[sl] * dinv[(r << 12) + sl];
            swl[s16][idx] = w;
            swsum += w;
        }
        for (int o = 32; o; o >>= 1) swsum += __shfl_down(swsum, o);
        if (lane == 0) ssw[s16] = swsum;
    }
    __syncthreads();
    // aggregate: wave wv owns slots base+4wv .. +3; lane covers 4 cols (float4)
    int c4 = lane << 2;
    for (int j = 0; j < 4; ++j) {
        int s16 = (wv << 2) + j;
        int slot = base + s16;
        if (slot >= U) { *(float4*)&ys[s16][c4] = make_float4(0.f, 0.f, 0.f, 0.f); continue; }
        int n = sn[s16];
        float di = sdii[s16];
        float4 v = ((const float4*)(feat + (size_t)nodeof[slot] * IN_DIM))[lane];
        float4 acc;
        acc.x = di * v.x; acc.y = di * v.y; acc.z = di * v.z; acc.w = di * v.w;
        #pragma unroll 4
        for (int k = 0; k < n; ++k) {
            float w = swl[s16][k];
            float4 x = ((const float4*)(feat + (size_t)snode[s16][k] * IN_DIM))[lane];
            acc.x += w * x.x; acc.y += w * x.y; acc.z += w * x.z; acc.w += w * x.w;
        }
        float f = di * (di + ssw[s16]);
        float4 a4 = *(const float4*)(af + c4);
        float4 b4 = *(const float4*)(bfv + c4);
        float4 o;
        o.x = a4.x * (acc.x * di) + b4.x * f;
        o.y = a4.y * (acc.y * di) + b4.y * f;
        o.z = a4.z * (acc.z * di) + b4.z * f;
        o.w = a4.w * (acc.w * di) + b4.w * f;
        *(float4*)&ys[s16][c4] = o;
    }
    __syncthreads();
    // MLP: thread -> col c = t&127, group g = t>>7 covers slots g*8..g*8+7
    int c = t & 127, g = t >> 7;
    float acc[8] = {0.f};
    for (int k = 0; k < IN_DIM; ++k) {
        float wvl = w1[k * HID + c];
        #pragma unroll
        for (int j = 0; j < 8; ++j) acc[j] += ys[g * 8 + j][k] * wvl;
    }
    #pragma unroll
    for (int j = 0; j < 8; ++j) {
        int slot = base + g * 8 + j;
        if (slot < U) {
            float z = acc[j];
            float e = z > 0.f ? z : expm1f(z);            // elu
            h1[((size_t)(r << 12) + slot) * HID + c] = 1.f / (1.f + expf(-e));  // sigmoid
        }
    }
}

// ---- fused agg2+mlp2: 16 slots/block; agg h1 -> LDS -> GEMM + elu ----
__global__ __launch_bounds__(256) void aggmlp2_k(const float* __restrict__ h1,
                                                 const unsigned* __restrict__ cols,
                                                 const int* __restrict__ cnt,
                                                 const float* __restrict__ dinv,
                                                 const float* __restrict__ multf,
                                                 const int* __restrict__ Ucnt,
                                                 const float* __restrict__ w2,
                                                 float* __restrict__ h2) {
    int blk = blockIdx.x;                 // r*256 + chunk
    int r = blk >> 8, base = (blk & 255) << 4;
    int U = *Ucnt;
    if (base >= U) return;
    int t = threadIdx.x, lane = t & 63, wv = t >> 6;
    __shared__ unsigned short scl[16][CAPD];     // 4 KB (slot ids)
    __shared__ float swl[16][CAPD];              // 8 KB
    __shared__ float ys[16][HID];                // 8 KB
    __shared__ float sdii[16];
    __shared__ int sn[16];
    for (int s16 = wv; s16 < 16; s16 += 4) {
        int slot = base + s16;
        int n = (slot < U) ? cnt[(r << 12) + slot] : 0;
        if (lane == 0) { sn[s16] = n; sdii[s16] = (slot < U) ? dinv[(r << 12) + slot] : 0.f; }
        size_t cb = ((size_t)(r << 12) + slot) * CAPD;
        for (int idx = lane; idx < n; idx += 64) {
            unsigned e = cols[cb + idx];
            int sl = e >> 13;
            scl[s16][idx] = (unsigned short)sl;
            swl[s16][idx] = multf[sl] * dinv[(r << 12) + sl];
        }
    }
    __syncthreads();
    const float* h1r = h1 + ((size_t)(r << 12)) * HID;
    int c2 = lane << 1;
    for (int j = 0; j < 4; ++j) {
        int s16 = (wv << 2) + j;
        int slot = base + s16;
        if (slot >= U) { ys[s16][c2] = 0.f; ys[s16][c2 + 1] = 0.f; continue; }
        int n = sn[s16];
        float di = sdii[s16];
        float2 v = ((const float2*)(h1r + (size_t)slot * HID))[lane];
        float ax = di * v.x, ay = di * v.y;
        #pragma unroll 4
        for (int k = 0; k < n; ++k) {
            float w = swl[s16][k];
            float2 x = ((const float2*)(h1r + (size_t)scl[s16][k] * HID))[lane];
            ax += w * x.x; ay += w * x.y;
        }
        ys[s16][c2] = ax * di;
        ys[s16][c2 + 1] = ay * di;
    }
    __syncthreads();
    // MLP2: thread -> col c = t&63, group g = t>>6 covers slots g*4..g*4+3
    int c = t & 63, g = t >> 6;
    float acc[4] = {0.f};
    for (int k = 0; k < HID; ++k) {
        float wvl = w2[k * OUT + c];
        #pragma unroll
        for (int j = 0; j < 4; ++j) acc[j] += ys[g * 4 + j][k] * wvl;
    }
    #pragma unroll
    for (int j = 0; j < 4; ++j) {
        int slot = base + g * 4 + j;
        if (slot < U) {
            float z = acc[j];
            h2[((size_t)(r << 12) + slot) * OUT + c] = z > 0.f ? z : expm1f(z);  // elu
        }
    }
}

// ---- BN2 stats per (relation, column): multiplicity-weighted over slots ----
__global__ __launch_bounds__(256) void bn2_stats_k(const float* __restrict__ h2,
                                                   const float* __restrict__ multf,
                                                   const int* __restrict__ Ucnt,
                                                   float* __restrict__ m2,
                                                   float* __restrict__ rs2) {
    int ro = blockIdx.x;             // r*OUT + o
    int r = ro >> 6, o = ro & (OUT - 1);
    int U = *Ucnt;
    float s = 0.f, q = 0.f;
    for (int sl = threadIdx.x; sl < U; sl += 256) {
        float m = multf[sl];
        float v = h2[(size_t)((r << 12) + sl) * OUT + o];
        s += m * v; q += m * v * v;
    }
    int lane = threadIdx.x & 63, wv = threadIdx.x >> 6;
    for (int off = 32; off; off >>= 1) { s += __shfl_down(s, off); q += __shfl_down(q, off); }
    __shared__ float ps[4], pq[4];
    if (lane == 0) { ps[wv] = s; pq[wv] = q; }
    __syncthreads();
    if (threadIdx.x == 0) {
        float S = ps[0] + ps[1] + ps[2] + ps[3];
        float Q = pq[0] + pq[1] + pq[2] + pq[3];
        float m = S / BB;                 // sum of mult == BB positions
        float v = Q / BB - m * m;
        m2[ro] = m;
        rs2[ro] = rsqrtf(v + EPS);
    }
}

// ---- finalize: out[i] = relu(mean_r BN2(h2[r, slot(i)])) ----
__global__ __launch_bounds__(256) void finalize_k(const float* __restrict__ h2,
                                                  const unsigned short* __restrict__ pos2slot,
                                                  const float* __restrict__ m2,
                                                  const float* __restrict__ rs2,
                                                  const float* __restrict__ g2,
                                                  const float* __restrict__ b2,
                                                  float* __restrict__ out) {
    int idx = blockIdx.x * 256 + threadIdx.x;  // i*OUT + o
    if (idx >= BB * OUT) return;
    int i = idx >> 6, o = idx & (OUT - 1);
    int sl = pos2slot[i];
    float s = 0.f;
    for (int r = 0; r < RR; ++r) {
        float v = h2[(size_t)((r << 12) + sl) * OUT + o];
        s += (v - m2[r * OUT + o]) * rs2[r * OUT + o] * g2[o] + b2[o];
    }
    s *= (1.0f / RR);
    out[idx] = s > 0.f ? s : 0.f;
}

extern "C" void kernel_launch(void* const* d_in, const int* in_sizes, int n_in,
                              void* d_out, int out_size, void* d_ws, size_t ws_size,
                              hipStream_t stream) {
    const float* feat = (const float*)d_in[0];
    const float* adj  = (const float*)d_in[1];
    const int*   bn   = (const int*)d_in[2];
    const float* w1   = (const float*)d_in[3];
    const float* w2   = (const float*)d_in[4];
    const float* g1   = (const float*)d_in[5];
    const float* b1   = (const float*)d_in[6];
    const float* g2   = (const float*)d_in[7];
    const float* b2   = (const float*)d_in[8];
    float* out = (float*)d_out;

    // workspace layout (256-aligned offsets)
    char* ws = (char*)d_ws;
    size_t off = 0;
    auto alloc = [&](size_t bytes) { size_t o = off; off += (bytes + 255) & ~(size_t)255; return o; };
    unsigned long long* memb = (unsigned long long*)(ws + alloc(MWN * 8));      // 1 KB
    unsigned short* rankg    = (unsigned short*)(ws + alloc(NN * 2));           // 16 KB
    unsigned short* nodeof   = (unsigned short*)(ws + alloc(BB * 2));           // 8 KB
    float* multf             = (float*)(ws + alloc(BB * 4));                    // 16 KB
    int* Ucnt                = (int*)(ws + alloc(4));
    unsigned short* pos2slot = (unsigned short*)(ws + alloc(BB * 2));           // 8 KB
    float* af                = (float*)(ws + alloc(IN_DIM * 4));
    float* bfv               = (float*)(ws + alloc(IN_DIM * 4));
    float* m2                = (float*)(ws + alloc(RR * OUT * 4));
    float* rs2               = (float*)(ws + alloc(RR * OUT * 4));
    unsigned* cols           = (unsigned*)(ws + alloc((size_t)RR * BB * CAPD * 4)); // 6.3 MB
    int* cnt                 = (int*)(ws + alloc((size_t)RR * BB * 4));         // 48 KB
    float* dinv              = (float*)(ws + alloc((size_t)RR * BB * 4));       // 48 KB
    float* h1                = (float*)(ws + alloc((size_t)RR * BB * HID * 4)); // 6.3 MB
    float* h2                = (float*)(ws + alloc((size_t)RR * BB * OUT * 4)); // 3.1 MB

    k1_bn1_prep_k<<<IN_DIM + 1, 256, 0, stream>>>(feat, bn, g1, b1, af, bfv,
                                                  memb, rankg, nodeof, multf, Ucnt, pos2slot);
    build_k<<<RR * BB, 256, 0, stream>>>(adj, nodeof, Ucnt, memb, rankg, multf, cols, cnt, dinv);
    aggmlp1_k<<<RR * (BB / 16), 256, 0, stream>>>(feat, cols, cnt, dinv, multf, nodeof, Ucnt,
                                                  af, bfv, w1, h1);
    aggmlp2_k<<<RR * (BB / 16), 256, 0, stream>>>(h1, cols, cnt, dinv, multf, Ucnt, w2, h2);
    bn2_stats_k<<<RR * OUT, 256, 0, stream>>>(h2, multf, Ucnt, m2, rs2);
    finalize_k<<<(BB * OUT + 255) / 256, 256, 0, stream>>>(h2, pos2slot, m2, rs2, g2, b2, out);
}